// Round 13
// baseline (1461.129 us; speedup 1.0000x reference)
//
#include <hip/hip_runtime.h>
#include <math.h>

#define NB 8
#define NS 32
#define NN 2048
#define ND 64
#define NH 128
#define NE 32768
#define NT (NB*NN)
#define LN_EPS 1e-5f

typedef __attribute__((ext_vector_type(8))) short short8v;
typedef __attribute__((ext_vector_type(4))) float f32x4;
typedef __attribute__((ext_vector_type(4))) unsigned int u32x4;

static __device__ inline unsigned short f2bf(float f) {
  union { float f; unsigned int u; } v; v.f = f;
  unsigned int r = v.u + 0x7fffu + ((v.u >> 16) & 1u);
  return (unsigned short)(r >> 16);
}
static __device__ inline float bf2f(unsigned short s) {
  union { unsigned int u; float f; } v; v.u = ((unsigned int)s) << 16;
  return v.f;
}

static __device__ inline void acc_raw(u32x4 r, float* acc) {
#pragma unroll
  for (int i = 0; i < 4; i++) {
    union { unsigned int u; float x; } lo, hi;
    lo.u = r[i] << 16; hi.u = r[i] & 0xFFFF0000u;
    acc[2*i] += lo.x; acc[2*i+1] += hi.x;
  }
}

// 8-deep register-staged row-sum gather: rows of 'base' at (sn*stride + foff),
// sn from uniform csr_src[k0..k1). 8 loads in flight before any conversion.
static __device__ inline void gather8(const unsigned short* __restrict__ base,
                                      size_t stride, int foff,
                                      const int* __restrict__ csr_src,
                                      int k0, int k1, float* acc) {
  int k = k0;
  while (k + 8 <= k1) {
    u32x4 raw[8];
#pragma unroll
    for (int t = 0; t < 8; t++) {
      int sn = csr_src[k + t];          // uniform -> s_load
      raw[t] = *(const u32x4*)(base + (size_t)sn * stride + foff);
    }
#pragma unroll
    for (int t = 0; t < 8; t++) acc_raw(raw[t], acc);
    k += 8;
  }
  if (k + 4 <= k1) {
    u32x4 raw[4];
#pragma unroll
    for (int t = 0; t < 4; t++) {
      int sn = csr_src[k + t];
      raw[t] = *(const u32x4*)(base + (size_t)sn * stride + foff);
    }
#pragma unroll
    for (int t = 0; t < 4; t++) acc_raw(raw[t], acc);
    k += 4;
  }
  while (k < k1) {
    int sn = csr_src[k];
    u32x4 r = *(const u32x4*)(base + (size_t)sn * stride + foff);
    acc_raw(r, acc);
    k++;
  }
}

// ---------------- CSR build (topology is time-invariant) ----------------

__global__ void k_count(const int* __restrict__ dst, int* __restrict__ deg) {
  int e = blockIdx.x * blockDim.x + threadIdx.x;
  if (e < NE) atomicAdd(&deg[dst[e]], 1);
}

__global__ void k_scan(const int* __restrict__ deg, int* __restrict__ row_start,
                       float* __restrict__ dinv, float* __restrict__ dsq) {
  if (threadIdx.x == 0) {
    int acc = 0;
    for (int n = 0; n < NN; n++) { row_start[n] = acc; acc += deg[n]; }
    row_start[NN] = acc;
  }
  for (int n = threadIdx.x; n < NN; n += blockDim.x) {
    float d = (float)(deg[n] + 1);
    dinv[n] = rsqrtf(d);       // +1 self loop; always > 0
    dsq[n]  = sqrtf(d);        // 1/dinv, for un-scaling
  }
}

__global__ void k_scatter(const int* __restrict__ src, const int* __restrict__ dst,
                          const int* __restrict__ row_start, int* __restrict__ cursor,
                          int* __restrict__ csr_src) {
  int e = blockIdx.x * blockDim.x + threadIdx.x;
  if (e < NE) {
    int d = dst[e];
    int pos = atomicAdd(&cursor[d], 1);
    csr_src[row_start[d] + pos] = src[e];
  }
}

// ---------------- weight transpose + bf16 convert (once) ----------------

__global__ void k_wcvt(const float* __restrict__ Wz, const float* __restrict__ Wr,
                       const float* __restrict__ Wc,
                       unsigned short* __restrict__ Wt_zr, unsigned short* __restrict__ Wt_c) {
  int col = blockIdx.x;   // 0..255
  int k = threadIdx.x;    // 0..191
  float v = (col < 128) ? Wz[k * 128 + col] : Wr[k * 128 + (col - 128)];
  Wt_zr[(size_t)col * 192 + k] = f2bf(v);
  if (col < 128) Wt_c[(size_t)col * 192 + k] = f2bf(Wc[k * 128 + col]);
}

// ---------------- transpose x -> xTs[s][n][b][64] = dinv[n]*x (bf16) -------

__global__ __launch_bounds__(256)
void k_xT(const float* __restrict__ x, const float* __restrict__ dinv,
          unsigned short* __restrict__ xT) {
  int blk = blockIdx.x;          // 16384 blocks: (s, group of 4 n)
  int s = blk >> 9;
  int n0 = (blk & 511) * 4;
  int t = threadIdx.x;
  int b = t >> 5;
  int d2 = (t & 31) * 2;
#pragma unroll
  for (int i = 0; i < 4; i++) {
    int n = n0 + i;
    float dn = dinv[n];
    const float2 v = *(const float2*)(x + (((size_t)b * NS + s) * NN + n) * ND + d2);
    unsigned int p = ((unsigned int)f2bf(dn * v.y) << 16) | f2bf(dn * v.x);
    *(unsigned int*)(xT + (((size_t)s * NN + n) * NB + b) * ND + d2) = p;
  }
}

// ---------------- Xa[s][n][b][64] = A_hat @ x (all steps) -----------------

__global__ __launch_bounds__(256, 4)
void k_aggX2(const unsigned short* __restrict__ xT, const int* __restrict__ row_start,
             const int* __restrict__ csr_src, const float* __restrict__ dinv,
             unsigned short* __restrict__ Xa) {
  int bid = blockIdx.x;                     // 16384
  int bs = (bid & 7) * 2048 + (bid >> 3);   // XCD chunking
  int rid = bs * 4 + (threadIdx.x >> 6);    // (s,n) id
  int lane = threadIdx.x & 63;
  int s = rid >> 11;
  int n = __builtin_amdgcn_readfirstlane(rid & 2047);
  const unsigned short* xs = xT + (size_t)s * (NN * NB * ND);
  float dn = dinv[n];
  float acc[8];
  {
    u32x4 r0 = *(const u32x4*)(xs + (size_t)n * 512 + lane * 8);
#pragma unroll
    for (int i = 0; i < 8; i++) acc[i] = 0.f;
    acc_raw(r0, acc);
  }
  int k0 = __builtin_amdgcn_readfirstlane(row_start[n]);
  int k1 = __builtin_amdgcn_readfirstlane(row_start[n + 1]);
  gather8(xs, 512, lane * 8, csr_src, k0, k1, acc);
  unsigned int pk[4];
#pragma unroll
  for (int i = 0; i < 4; i++)
    pk[i] = ((unsigned int)f2bf(dn * acc[2*i+1]) << 16) | f2bf(dn * acc[2*i]);
  *(u32x4*)(Xa + (size_t)rid * 512 + lane * 8) = *(u32x4*)pk;
}

// ---------------- phase A: agg(hBs) + [Xa|ha]@[Wz|Wr] + gates ---------------
// hBs = dinv ⊙ h (pre-scaled state). rhBs = sigmoid(r) ⊙ hBs.
// 256 thr = 4 waves, 2 nodes/block. Gather: wave w -> node j=w>>1, half=w&1.

__global__ __launch_bounds__(256, 4)
void k_zrF(const unsigned short* __restrict__ Xa, const unsigned short* __restrict__ hB,
           const unsigned short* __restrict__ Wt,
           const int* __restrict__ row_start, const int* __restrict__ csr_src,
           const float* __restrict__ dinv,
           const float* __restrict__ bz, const float* __restrict__ br,
           _Float16* __restrict__ zH, unsigned short* __restrict__ rhB, int s) {
  __shared__ unsigned short ha[16 * 128];
  int tid = threadIdx.x;
  int lane = tid & 63;
  int w = tid >> 6;
  int n0 = blockIdx.x * 2;
  int j = w >> 1, half = w & 1;
  int n = __builtin_amdgcn_readfirstlane(n0 + j);
  float dn = dinv[n];
  float acc[8];
  int foff = half * 512 + lane * 8;         // element in [0,1024) of node row
  {
    u32x4 r0 = *(const u32x4*)(hB + (size_t)n * (NB * NH) + foff);
#pragma unroll
    for (int i = 0; i < 8; i++) acc[i] = 0.f;
    acc_raw(r0, acc);
  }
  int k0 = __builtin_amdgcn_readfirstlane(row_start[n]);
  int k1 = __builtin_amdgcn_readfirstlane(row_start[n + 1]);
  gather8(hB, NB * NH, foff, csr_src, k0, k1, acc);
  {  // LDS [16][128] bf16, XOR-swizzled; row = j*8 + b
    int row = j * 8 + (foff >> 7);
    int fe = foff & 127;
    unsigned int pk[4];
#pragma unroll
    for (int i = 0; i < 4; i++)
      pk[i] = ((unsigned int)f2bf(dn * acc[2*i+1]) << 16) | f2bf(dn * acc[2*i]);
    int byte = (row * 256 + fe * 2) ^ ((row & 7) << 4);
    *(u32x4*)((char*)ha + byte) = *(u32x4*)pk;
  }
  __syncthreads();
  // ---- GEMM 16 rows x 256 cols
  int ar = lane & 15;
  int koff = (lane >> 4) * 8;
  short8v afr[6];
  const unsigned short* xrow =
      Xa + (((size_t)s * NN + n0 + (ar >> 3)) * NB + (ar & 7)) * ND;
  afr[0] = *(const short8v*)(xrow + koff);
  afr[1] = *(const short8v*)(xrow + 32 + koff);
#pragma unroll
  for (int kb = 2; kb < 6; kb++) {
    int kk = (kb - 2) * 32 + koff;
    int byte = (ar * 256 + kk * 2) ^ ((ar & 7) << 4);
    afr[kb] = *(const short8v*)((char*)ha + byte);
  }
  f32x4 cacc[4];
#pragma unroll
  for (int ct = 0; ct < 4; ct++) cacc[ct] = (f32x4){0.f, 0.f, 0.f, 0.f};
#pragma unroll
  for (int ct = 0; ct < 4; ct++) {
    const unsigned short* wcol = Wt + (size_t)((w * 4 + ct) * 16 + (lane & 15)) * 192;
#pragma unroll
    for (int kb = 0; kb < 6; kb++) {
      short8v bfr = *(const short8v*)(wcol + kb * 32 + koff);
      cacc[ct] = __builtin_amdgcn_mfma_f32_16x16x32_bf16(afr[kb], bfr, cacc[ct], 0, 0, 0);
    }
  }
  // ---- epilogue: cols 0-127 -> z (fp16); cols 128-255 -> rhBs = sig(r)*hBs
  int r0 = (lane >> 4) * 4;
#pragma unroll
  for (int ct = 0; ct < 4; ct++) {
    int col = (w * 4 + ct) * 16 + (lane & 15);
    int isz = (col < 128);
    int f = isz ? col : col - 128;
    float bias = isz ? bz[f] : br[f];
#pragma unroll
    for (int qq = 0; qq < 4; qq++) {
      int r = r0 + qq;
      size_t gidx = (((size_t)(n0 + (r >> 3))) * NB + (r & 7)) * NH + f;
      float g = cacc[ct][qq] + bias;
      float sg = 1.f / (1.f + __expf(-g));
      if (isz) zH[gidx] = (_Float16)sg;
      else rhB[gidx] = f2bf(sg * bf2f(hB[gidx]));
    }
  }
}

// ---------------- phase B: agg(rhBs) + @Wc + tanh + gate + LN ---------------

__global__ __launch_bounds__(256, 4)
void k_cF(const unsigned short* __restrict__ Xa, const unsigned short* __restrict__ rhB,
          const _Float16* __restrict__ zH, const unsigned short* __restrict__ Wt,
          const int* __restrict__ row_start, const int* __restrict__ csr_src,
          const float* __restrict__ dinv, const float* __restrict__ dsq,
          const float* __restrict__ bc,
          const float* __restrict__ gamma, const float* __restrict__ beta,
          unsigned short* __restrict__ hB, int s) {
  __shared__ unsigned short rha[16 * 128];
  __shared__ float lsum[4][16], lsq[4][16];
  int tid = threadIdx.x;
  int lane = tid & 63;
  int w = tid >> 6;
  int n0 = blockIdx.x * 2;
  int j = w >> 1, half = w & 1;
  int n = __builtin_amdgcn_readfirstlane(n0 + j);
  float dn = dinv[n];
  float acc[8];
  int foff = half * 512 + lane * 8;
  {
    u32x4 r0 = *(const u32x4*)(rhB + (size_t)n * (NB * NH) + foff);
#pragma unroll
    for (int i = 0; i < 8; i++) acc[i] = 0.f;
    acc_raw(r0, acc);
  }
  int k0 = __builtin_amdgcn_readfirstlane(row_start[n]);
  int k1 = __builtin_amdgcn_readfirstlane(row_start[n + 1]);
  gather8(rhB, NB * NH, foff, csr_src, k0, k1, acc);
  {
    int row = j * 8 + (foff >> 7);
    int fe = foff & 127;
    unsigned int pk[4];
#pragma unroll
    for (int i = 0; i < 4; i++)
      pk[i] = ((unsigned int)f2bf(dn * acc[2*i+1]) << 16) | f2bf(dn * acc[2*i]);
    int byte = (row * 256 + fe * 2) ^ ((row & 7) << 4);
    *(u32x4*)((char*)rha + byte) = *(u32x4*)pk;
  }
  __syncthreads();
  int ar = lane & 15;
  int koff = (lane >> 4) * 8;
  short8v afr[6];
  const unsigned short* xrow =
      Xa + (((size_t)s * NN + n0 + (ar >> 3)) * NB + (ar & 7)) * ND;
  afr[0] = *(const short8v*)(xrow + koff);
  afr[1] = *(const short8v*)(xrow + 32 + koff);
#pragma unroll
  for (int kb = 2; kb < 6; kb++) {
    int kk = (kb - 2) * 32 + koff;
    int byte = (ar * 256 + kk * 2) ^ ((ar & 7) << 4);
    afr[kb] = *(const short8v*)((char*)rha + byte);
  }
  f32x4 cacc[2];
  cacc[0] = (f32x4){0.f, 0.f, 0.f, 0.f};
  cacc[1] = (f32x4){0.f, 0.f, 0.f, 0.f};
#pragma unroll
  for (int ct = 0; ct < 2; ct++) {
    const unsigned short* wcol = Wt + (size_t)((w * 2 + ct) * 16 + (lane & 15)) * 192;
#pragma unroll
    for (int kb = 0; kb < 6; kb++) {
      short8v bfr = *(const short8v*)(wcol + kb * 32 + koff);
      cacc[ct] = __builtin_amdgcn_mfma_f32_16x16x32_bf16(afr[kb], bfr, cacc[ct], 0, 0, 0);
    }
  }
  // ---- epilogue: tanh, gate, LN
  int r0 = (lane >> 4) * 4;
  float dq0 = dsq[n0], dq1 = dsq[n0 + 1];
  float di0 = dinv[n0], di1 = dinv[n0 + 1];
  float u[2][4];
  float psum[4] = {0.f, 0.f, 0.f, 0.f};
  float psq[4] = {0.f, 0.f, 0.f, 0.f};
#pragma unroll
  for (int ct = 0; ct < 2; ct++) {
    int col = (w * 2 + ct) * 16 + (lane & 15);
    float bcc = bc[col];
#pragma unroll
    for (int qq = 0; qq < 4; qq++) {
      int r = r0 + qq;
      float dq = (r >> 3) ? dq1 : dq0;
      size_t gidx = (((size_t)(n0 + (r >> 3))) * NB + (r & 7)) * NH + col;
      float gc = cacc[ct][qq] + bcc;
      float ea = __expf(-2.f * fabsf(gc));
      float th = (1.f - ea) / (1.f + ea);
      float cand = copysignf(th, gc);
      float zv = (float)zH[gidx];
      float uu = (1.f - zv) * (bf2f(hB[gidx]) * dq) + zv * cand;
      u[ct][qq] = uu;
      psum[qq] += uu; psq[qq] += uu * uu;
    }
  }
#pragma unroll
  for (int qq = 0; qq < 4; qq++) {
    float s1 = psum[qq], s2 = psq[qq];
#pragma unroll
    for (int o = 1; o <= 8; o <<= 1) {
      s1 += __shfl_xor(s1, o, 64);
      s2 += __shfl_xor(s2, o, 64);
    }
    if ((lane & 15) == 0) {
      lsum[w][r0 + qq] = s1; lsq[w][r0 + qq] = s2;
    }
  }
  __syncthreads();
#pragma unroll
  for (int ct = 0; ct < 2; ct++) {
    int col = (w * 2 + ct) * 16 + (lane & 15);
    float g = gamma[col], bt = beta[col];
#pragma unroll
    for (int qq = 0; qq < 4; qq++) {
      int r = r0 + qq;
      float di = (r >> 3) ? di1 : di0;
      float tot = lsum[0][r] + lsum[1][r] + lsum[2][r] + lsum[3][r];
      float totq = lsq[0][r] + lsq[1][r] + lsq[2][r] + lsq[3][r];
      float mu = tot * (1.f / NH);
      float var = totq * (1.f / NH) - mu * mu;
      float inv = rsqrtf(var + LN_EPS);
      float hv = (u[ct][qq] - mu) * inv * g + bt;
      size_t gidx = (((size_t)(n0 + (r >> 3))) * NB + (r & 7)) * NH + col;
      hB[gidx] = f2bf(hv * di);
    }
  }
}

// ---------------- pool: out[b][f] = mean_n h[n][b][f]; h = hBs * dsq -------

__global__ __launch_bounds__(128)
void k_pool(const unsigned short* __restrict__ hB, const float* __restrict__ dsq,
            float* __restrict__ out) {
  int b = blockIdx.x & 7;
  int c = blockIdx.x >> 3;   // 16 chunks of 128 nodes
  int f = threadIdx.x;
  float acc = 0.f;
  for (int n = c * 128; n < c * 128 + 128; n++)
    acc += bf2f(hB[((size_t)n * NB + b) * NH + f]) * dsq[n];
  atomicAdd(&out[b * NH + f], acc * (1.f / NN));
}

// ---------------- host ----------------------------------------------------

extern "C" void kernel_launch(void* const* d_in, const int* in_sizes, int n_in,
                              void* d_out, int out_size, void* d_ws, size_t ws_size,
                              hipStream_t stream) {
  const float* x     = (const float*)d_in[0];
  const int*   ei    = (const int*)d_in[1];
  const float* Wz    = (const float*)d_in[3];
  const float* bz    = (const float*)d_in[4];
  const float* Wr    = (const float*)d_in[5];
  const float* br    = (const float*)d_in[6];
  const float* Wc    = (const float*)d_in[7];
  const float* bc    = (const float*)d_in[8];
  const float* gamma = (const float*)d_in[9];
  const float* beta  = (const float*)d_in[10];
  float* out = (float*)d_out;

  char* ws = (char*)d_ws;
  size_t off = 0;
  auto alloc = [&](size_t bytes) {
    void* p = ws + off;
    off = (off + bytes + 255) & ~(size_t)255;
    return p;
  };
  unsigned short* hB   = (unsigned short*)alloc((size_t)NT * NH * 2);
  unsigned short* rhB  = (unsigned short*)alloc((size_t)NT * NH * 2);
  _Float16*       zH   = (_Float16*)alloc((size_t)NT * NH * 2);
  unsigned short* xT   = (unsigned short*)alloc((size_t)NS * NN * NB * ND * 2);
  unsigned short* Xa   = (unsigned short*)alloc((size_t)NS * NN * NB * ND * 2);
  unsigned short* Wt_zr = (unsigned short*)alloc((size_t)256 * 192 * 2);
  unsigned short* Wt_c  = (unsigned short*)alloc((size_t)128 * 192 * 2);
  float* dinv = (float*)alloc(NN * 4);
  float* dsq  = (float*)alloc(NN * 4);
  int* deg       = (int*)alloc(NN * 4);
  int* row_start = (int*)alloc((NN + 1) * 4);
  int* cursor    = (int*)alloc(NN * 4);
  int* csr_src   = (int*)alloc(NE * 4);

  const int* e_src = ei;
  const int* e_dst = ei + NE;

  hipMemsetAsync(hB, 0, (size_t)NT * NH * 2, stream);
  hipMemsetAsync(deg, 0, NN * 4, stream);
  hipMemsetAsync(cursor, 0, NN * 4, stream);
  hipMemsetAsync(d_out, 0, (size_t)NB * NH * 4, stream);

  k_count<<<NE / 256, 256, 0, stream>>>(e_dst, deg);
  k_scan<<<1, 256, 0, stream>>>(deg, row_start, dinv, dsq);
  k_scatter<<<NE / 256, 256, 0, stream>>>(e_src, e_dst, row_start, cursor, csr_src);
  k_wcvt<<<256, 192, 0, stream>>>(Wz, Wr, Wc, Wt_zr, Wt_c);
  k_xT<<<16384, 256, 0, stream>>>(x, dinv, xT);
  k_aggX2<<<16384, 256, 0, stream>>>(xT, row_start, csr_src, dinv, Xa);

  for (int s = 0; s < NS; s++) {
    k_zrF<<<NN / 2, 256, 0, stream>>>(Xa, hB, Wt_zr, row_start, csr_src, dinv,
                                      bz, br, zH, rhB, s);
    k_cF<<<NN / 2, 256, 0, stream>>>(Xa, rhB, zH, Wt_c, row_start, csr_src, dinv,
                                     dsq, bc, gamma, beta, hB, s);
  }
  k_pool<<<128, 128, 0, stream>>>(hB, dsq, out);
}

// Round 14
// 1459.558 us; speedup vs baseline: 1.0011x; 1.0011x over previous
//
#include <hip/hip_runtime.h>
#include <math.h>

#define NB 8
#define NS 32
#define NN 2048
#define ND 64
#define NH 128
#define NE 32768
#define NT (NB*NN)
#define LN_EPS 1e-5f

typedef __attribute__((ext_vector_type(8))) short short8v;
typedef __attribute__((ext_vector_type(4))) float f32x4;
typedef __attribute__((ext_vector_type(4))) unsigned int u32x4;

static __device__ inline unsigned short f2bf(float f) {
  union { float f; unsigned int u; } v; v.f = f;
  unsigned int r = v.u + 0x7fffu + ((v.u >> 16) & 1u);
  return (unsigned short)(r >> 16);
}
static __device__ inline float bf2f(unsigned short s) {
  union { unsigned int u; float f; } v; v.u = ((unsigned int)s) << 16;
  return v.f;
}

static __device__ inline void acc_raw(u32x4 r, float* acc) {
#pragma unroll
  for (int i = 0; i < 4; i++) {
    union { unsigned int u; float x; } lo, hi;
    lo.u = r[i] << 16; hi.u = r[i] & 0xFFFF0000u;
    acc[2*i] += lo.x; acc[2*i+1] += hi.x;
  }
}

// 8-deep register-staged row-sum gather.
static __device__ inline void gather8(const unsigned short* __restrict__ base,
                                      size_t stride, int foff,
                                      const int* __restrict__ csr_src,
                                      int k0, int k1, float* acc) {
  int k = k0;
  while (k + 8 <= k1) {
    u32x4 raw[8];
#pragma unroll
    for (int t = 0; t < 8; t++) {
      int sn = csr_src[k + t];          // uniform -> s_load
      raw[t] = *(const u32x4*)(base + (size_t)sn * stride + foff);
    }
#pragma unroll
    for (int t = 0; t < 8; t++) acc_raw(raw[t], acc);
    k += 8;
  }
  if (k + 4 <= k1) {
    u32x4 raw[4];
#pragma unroll
    for (int t = 0; t < 4; t++) {
      int sn = csr_src[k + t];
      raw[t] = *(const u32x4*)(base + (size_t)sn * stride + foff);
    }
#pragma unroll
    for (int t = 0; t < 4; t++) acc_raw(raw[t], acc);
    k += 4;
  }
  while (k < k1) {
    int sn = csr_src[k];
    u32x4 r = *(const u32x4*)(base + (size_t)sn * stride + foff);
    acc_raw(r, acc);
    k++;
  }
}

// ---------------- CSR build (topology is time-invariant) ----------------

__global__ void k_count(const int* __restrict__ dst, int* __restrict__ deg) {
  int e = blockIdx.x * blockDim.x + threadIdx.x;
  if (e < NE) atomicAdd(&deg[dst[e]], 1);
}

__global__ void k_scan(const int* __restrict__ deg, int* __restrict__ row_start,
                       float* __restrict__ dinv, float* __restrict__ dsq) {
  if (threadIdx.x == 0) {
    int acc = 0;
    for (int n = 0; n < NN; n++) { row_start[n] = acc; acc += deg[n]; }
    row_start[NN] = acc;
  }
  for (int n = threadIdx.x; n < NN; n += blockDim.x) {
    float d = (float)(deg[n] + 1);
    dinv[n] = rsqrtf(d);
    dsq[n]  = sqrtf(d);
  }
}

__global__ void k_scatter(const int* __restrict__ src, const int* __restrict__ dst,
                          const int* __restrict__ row_start, int* __restrict__ cursor,
                          int* __restrict__ csr_src) {
  int e = blockIdx.x * blockDim.x + threadIdx.x;
  if (e < NE) {
    int d = dst[e];
    int pos = atomicAdd(&cursor[d], 1);
    csr_src[row_start[d] + pos] = src[e];
  }
}

// ---------------- degree counting-sort: perm[i] = i-th lightest node --------
// single block; bins 0..255 (deg < 256 guaranteed: avg 16).

__global__ void k_perm(const int* __restrict__ deg, int* __restrict__ perm) {
  __shared__ int hist[256];
  __shared__ int base[256];
  int t = threadIdx.x;
  hist[t] = 0;
  __syncthreads();
  for (int n = t; n < NN; n += 256) {
    int d = deg[n]; if (d > 255) d = 255;
    atomicAdd(&hist[d], 1);
  }
  __syncthreads();
  if (t == 0) {
    int acc = 0;
    for (int i = 0; i < 256; i++) { base[i] = acc; acc += hist[i]; }
  }
  __syncthreads();
  for (int n = t; n < NN; n += 256) {
    int d = deg[n]; if (d > 255) d = 255;
    int pos = atomicAdd(&base[d], 1);
    perm[pos] = n;
  }
}

// ---------------- weight transpose + bf16 convert (once) ----------------

__global__ void k_wcvt(const float* __restrict__ Wz, const float* __restrict__ Wr,
                       const float* __restrict__ Wc,
                       unsigned short* __restrict__ Wt_zr, unsigned short* __restrict__ Wt_c) {
  int col = blockIdx.x;   // 0..255
  int k = threadIdx.x;    // 0..191
  float v = (col < 128) ? Wz[k * 128 + col] : Wr[k * 128 + (col - 128)];
  Wt_zr[(size_t)col * 192 + k] = f2bf(v);
  if (col < 128) Wt_c[(size_t)col * 192 + k] = f2bf(Wc[k * 128 + col]);
}

// ---------------- transpose x -> xTs[s][n][b][64] = dinv[n]*x (bf16) -------

__global__ __launch_bounds__(256)
void k_xT(const float* __restrict__ x, const float* __restrict__ dinv,
          unsigned short* __restrict__ xT) {
  int blk = blockIdx.x;          // 16384 blocks: (s, group of 4 n)
  int s = blk >> 9;
  int n0 = (blk & 511) * 4;
  int t = threadIdx.x;
  int b = t >> 5;
  int d2 = (t & 31) * 2;
#pragma unroll
  for (int i = 0; i < 4; i++) {
    int n = n0 + i;
    float dn = dinv[n];
    const float2 v = *(const float2*)(x + (((size_t)b * NS + s) * NN + n) * ND + d2);
    unsigned int p = ((unsigned int)f2bf(dn * v.y) << 16) | f2bf(dn * v.x);
    *(unsigned int*)(xT + (((size_t)s * NN + n) * NB + b) * ND + d2) = p;
  }
}

// ---------------- Xa[s][n][b][64] = A_hat @ x (all steps) -----------------

__global__ __launch_bounds__(256, 4)
void k_aggX2(const unsigned short* __restrict__ xT, const int* __restrict__ row_start,
             const int* __restrict__ csr_src, const float* __restrict__ dinv,
             unsigned short* __restrict__ Xa) {
  int bid = blockIdx.x;                     // 16384
  int bs = (bid & 7) * 2048 + (bid >> 3);   // XCD chunking
  int rid = bs * 4 + (threadIdx.x >> 6);    // (s,n) id
  int lane = threadIdx.x & 63;
  int s = rid >> 11;
  int n = __builtin_amdgcn_readfirstlane(rid & 2047);
  const unsigned short* xs = xT + (size_t)s * (NN * NB * ND);
  float dn = dinv[n];
  float acc[8];
  {
    u32x4 r0 = *(const u32x4*)(xs + (size_t)n * 512 + lane * 8);
#pragma unroll
    for (int i = 0; i < 8; i++) acc[i] = 0.f;
    acc_raw(r0, acc);
  }
  int k0 = __builtin_amdgcn_readfirstlane(row_start[n]);
  int k1 = __builtin_amdgcn_readfirstlane(row_start[n + 1]);
  gather8(xs, 512, lane * 8, csr_src, k0, k1, acc);
  unsigned int pk[4];
#pragma unroll
  for (int i = 0; i < 4; i++)
    pk[i] = ((unsigned int)f2bf(dn * acc[2*i+1]) << 16) | f2bf(dn * acc[2*i]);
  *(u32x4*)(Xa + (size_t)rid * 512 + lane * 8) = *(u32x4*)pk;
}

// ---------------- phase A: agg(hBs) + [Xa|ha]@[Wz|Wr] + gates ---------------
// Degree-balanced: block bid handles nodes perm[bid] (light) and
// perm[NN-1-bid] (heavy) -> per-block work ~constant, no tail block.

__global__ __launch_bounds__(256, 4)
void k_zrF(const unsigned short* __restrict__ Xa, const unsigned short* __restrict__ hB,
           const unsigned short* __restrict__ Wt,
           const int* __restrict__ row_start, const int* __restrict__ csr_src,
           const float* __restrict__ dinv, const int* __restrict__ perm,
           const float* __restrict__ bz, const float* __restrict__ br,
           _Float16* __restrict__ zH, unsigned short* __restrict__ rhB, int s) {
  __shared__ unsigned short ha[16 * 128];
  int tid = threadIdx.x;
  int lane = tid & 63;
  int w = tid >> 6;
  int bid = blockIdx.x;
  int pa = __builtin_amdgcn_readfirstlane(perm[bid]);
  int pb = __builtin_amdgcn_readfirstlane(perm[NN - 1 - bid]);
  int j = w >> 1, half = w & 1;
  int n = j ? pb : pa;
  float dn = dinv[n];
  float acc[8];
  int foff = half * 512 + lane * 8;
  {
    u32x4 r0 = *(const u32x4*)(hB + (size_t)n * (NB * NH) + foff);
#pragma unroll
    for (int i = 0; i < 8; i++) acc[i] = 0.f;
    acc_raw(r0, acc);
  }
  int k0 = __builtin_amdgcn_readfirstlane(row_start[n]);
  int k1 = __builtin_amdgcn_readfirstlane(row_start[n + 1]);
  gather8(hB, NB * NH, foff, csr_src, k0, k1, acc);
  {  // LDS [16][128] bf16, XOR-swizzled; row = j*8 + b
    int row = j * 8 + (foff >> 7);
    int fe = foff & 127;
    unsigned int pk[4];
#pragma unroll
    for (int i = 0; i < 4; i++)
      pk[i] = ((unsigned int)f2bf(dn * acc[2*i+1]) << 16) | f2bf(dn * acc[2*i]);
    int byte = (row * 256 + fe * 2) ^ ((row & 7) << 4);
    *(u32x4*)((char*)ha + byte) = *(u32x4*)pk;
  }
  __syncthreads();
  // ---- GEMM 16 rows x 256 cols; row r -> node nd[r>>3], batch r&7
  int ar = lane & 15;
  int koff = (lane >> 4) * 8;
  int nda = (ar >> 3) ? pb : pa;
  short8v afr[6];
  const unsigned short* xrow =
      Xa + (((size_t)s * NN + nda) * NB + (ar & 7)) * ND;
  afr[0] = *(const short8v*)(xrow + koff);
  afr[1] = *(const short8v*)(xrow + 32 + koff);
#pragma unroll
  for (int kb = 2; kb < 6; kb++) {
    int kk = (kb - 2) * 32 + koff;
    int byte = (ar * 256 + kk * 2) ^ ((ar & 7) << 4);
    afr[kb] = *(const short8v*)((char*)ha + byte);
  }
  f32x4 cacc[4];
#pragma unroll
  for (int ct = 0; ct < 4; ct++) cacc[ct] = (f32x4){0.f, 0.f, 0.f, 0.f};
#pragma unroll
  for (int ct = 0; ct < 4; ct++) {
    const unsigned short* wcol = Wt + (size_t)((w * 4 + ct) * 16 + (lane & 15)) * 192;
#pragma unroll
    for (int kb = 0; kb < 6; kb++) {
      short8v bfr = *(const short8v*)(wcol + kb * 32 + koff);
      cacc[ct] = __builtin_amdgcn_mfma_f32_16x16x32_bf16(afr[kb], bfr, cacc[ct], 0, 0, 0);
    }
  }
  // ---- epilogue
  int r0 = (lane >> 4) * 4;
#pragma unroll
  for (int ct = 0; ct < 4; ct++) {
    int col = (w * 4 + ct) * 16 + (lane & 15);
    int isz = (col < 128);
    int f = isz ? col : col - 128;
    float bias = isz ? bz[f] : br[f];
#pragma unroll
    for (int qq = 0; qq < 4; qq++) {
      int r = r0 + qq;
      int nd = (r >> 3) ? pb : pa;
      size_t gidx = ((size_t)nd * NB + (r & 7)) * NH + f;
      float g = cacc[ct][qq] + bias;
      float sg = 1.f / (1.f + __expf(-g));
      if (isz) zH[gidx] = (_Float16)sg;
      else rhB[gidx] = f2bf(sg * bf2f(hB[gidx]));
    }
  }
}

// ---------------- phase B: agg(rhBs) + @Wc + tanh + gate + LN ---------------

__global__ __launch_bounds__(256, 4)
void k_cF(const unsigned short* __restrict__ Xa, const unsigned short* __restrict__ rhB,
          const _Float16* __restrict__ zH, const unsigned short* __restrict__ Wt,
          const int* __restrict__ row_start, const int* __restrict__ csr_src,
          const float* __restrict__ dinv, const float* __restrict__ dsq,
          const int* __restrict__ perm, const float* __restrict__ bc,
          const float* __restrict__ gamma, const float* __restrict__ beta,
          unsigned short* __restrict__ hB, int s) {
  __shared__ unsigned short rha[16 * 128];
  __shared__ float lsum[4][16], lsq[4][16];
  int tid = threadIdx.x;
  int lane = tid & 63;
  int w = tid >> 6;
  int bid = blockIdx.x;
  int pa = __builtin_amdgcn_readfirstlane(perm[bid]);
  int pb = __builtin_amdgcn_readfirstlane(perm[NN - 1 - bid]);
  int j = w >> 1, half = w & 1;
  int n = j ? pb : pa;
  float dn = dinv[n];
  float acc[8];
  int foff = half * 512 + lane * 8;
  {
    u32x4 r0 = *(const u32x4*)(rhB + (size_t)n * (NB * NH) + foff);
#pragma unroll
    for (int i = 0; i < 8; i++) acc[i] = 0.f;
    acc_raw(r0, acc);
  }
  int k0 = __builtin_amdgcn_readfirstlane(row_start[n]);
  int k1 = __builtin_amdgcn_readfirstlane(row_start[n + 1]);
  gather8(rhB, NB * NH, foff, csr_src, k0, k1, acc);
  {
    int row = j * 8 + (foff >> 7);
    int fe = foff & 127;
    unsigned int pk[4];
#pragma unroll
    for (int i = 0; i < 4; i++)
      pk[i] = ((unsigned int)f2bf(dn * acc[2*i+1]) << 16) | f2bf(dn * acc[2*i]);
    int byte = (row * 256 + fe * 2) ^ ((row & 7) << 4);
    *(u32x4*)((char*)rha + byte) = *(u32x4*)pk;
  }
  __syncthreads();
  int ar = lane & 15;
  int koff = (lane >> 4) * 8;
  int nda = (ar >> 3) ? pb : pa;
  short8v afr[6];
  const unsigned short* xrow =
      Xa + (((size_t)s * NN + nda) * NB + (ar & 7)) * ND;
  afr[0] = *(const short8v*)(xrow + koff);
  afr[1] = *(const short8v*)(xrow + 32 + koff);
#pragma unroll
  for (int kb = 2; kb < 6; kb++) {
    int kk = (kb - 2) * 32 + koff;
    int byte = (ar * 256 + kk * 2) ^ ((ar & 7) << 4);
    afr[kb] = *(const short8v*)((char*)rha + byte);
  }
  f32x4 cacc[2];
  cacc[0] = (f32x4){0.f, 0.f, 0.f, 0.f};
  cacc[1] = (f32x4){0.f, 0.f, 0.f, 0.f};
#pragma unroll
  for (int ct = 0; ct < 2; ct++) {
    const unsigned short* wcol = Wt + (size_t)((w * 2 + ct) * 16 + (lane & 15)) * 192;
#pragma unroll
    for (int kb = 0; kb < 6; kb++) {
      short8v bfr = *(const short8v*)(wcol + kb * 32 + koff);
      cacc[ct] = __builtin_amdgcn_mfma_f32_16x16x32_bf16(afr[kb], bfr, cacc[ct], 0, 0, 0);
    }
  }
  // ---- epilogue: tanh, gate, LN
  int r0 = (lane >> 4) * 4;
  float dq0 = dsq[pa], dq1 = dsq[pb];
  float di0 = dinv[pa], di1 = dinv[pb];
  float u[2][4];
  float psum[4] = {0.f, 0.f, 0.f, 0.f};
  float psq[4] = {0.f, 0.f, 0.f, 0.f};
#pragma unroll
  for (int ct = 0; ct < 2; ct++) {
    int col = (w * 2 + ct) * 16 + (lane & 15);
    float bcc = bc[col];
#pragma unroll
    for (int qq = 0; qq < 4; qq++) {
      int r = r0 + qq;
      int nd = (r >> 3) ? pb : pa;
      float dq = (r >> 3) ? dq1 : dq0;
      size_t gidx = ((size_t)nd * NB + (r & 7)) * NH + col;
      float gc = cacc[ct][qq] + bcc;
      float ea = __expf(-2.f * fabsf(gc));
      float th = (1.f - ea) / (1.f + ea);
      float cand = copysignf(th, gc);
      float zv = (float)zH[gidx];
      float uu = (1.f - zv) * (bf2f(hB[gidx]) * dq) + zv * cand;
      u[ct][qq] = uu;
      psum[qq] += uu; psq[qq] += uu * uu;
    }
  }
#pragma unroll
  for (int qq = 0; qq < 4; qq++) {
    float s1 = psum[qq], s2 = psq[qq];
#pragma unroll
    for (int o = 1; o <= 8; o <<= 1) {
      s1 += __shfl_xor(s1, o, 64);
      s2 += __shfl_xor(s2, o, 64);
    }
    if ((lane & 15) == 0) {
      lsum[w][r0 + qq] = s1; lsq[w][r0 + qq] = s2;
    }
  }
  __syncthreads();
#pragma unroll
  for (int ct = 0; ct < 2; ct++) {
    int col = (w * 2 + ct) * 16 + (lane & 15);
    float g = gamma[col], bt = beta[col];
#pragma unroll
    for (int qq = 0; qq < 4; qq++) {
      int r = r0 + qq;
      int nd = (r >> 3) ? pb : pa;
      float di = (r >> 3) ? di1 : di0;
      float tot = lsum[0][r] + lsum[1][r] + lsum[2][r] + lsum[3][r];
      float totq = lsq[0][r] + lsq[1][r] + lsq[2][r] + lsq[3][r];
      float mu = tot * (1.f / NH);
      float var = totq * (1.f / NH) - mu * mu;
      float inv = rsqrtf(var + LN_EPS);
      float hv = (u[ct][qq] - mu) * inv * g + bt;
      size_t gidx = ((size_t)nd * NB + (r & 7)) * NH + col;
      hB[gidx] = f2bf(hv * di);
    }
  }
}

// ---------------- pool: out[b][f] = mean_n h[n][b][f]; h = hBs * dsq -------

__global__ __launch_bounds__(128)
void k_pool(const unsigned short* __restrict__ hB, const float* __restrict__ dsq,
            float* __restrict__ out) {
  int b = blockIdx.x & 7;
  int c = blockIdx.x >> 3;   // 16 chunks of 128 nodes
  int f = threadIdx.x;
  float acc = 0.f;
  for (int n = c * 128; n < c * 128 + 128; n++)
    acc += bf2f(hB[((size_t)n * NB + b) * NH + f]) * dsq[n];
  atomicAdd(&out[b * NH + f], acc * (1.f / NN));
}

// ---------------- host ----------------------------------------------------

extern "C" void kernel_launch(void* const* d_in, const int* in_sizes, int n_in,
                              void* d_out, int out_size, void* d_ws, size_t ws_size,
                              hipStream_t stream) {
  const float* x     = (const float*)d_in[0];
  const int*   ei    = (const int*)d_in[1];
  const float* Wz    = (const float*)d_in[3];
  const float* bz    = (const float*)d_in[4];
  const float* Wr    = (const float*)d_in[5];
  const float* br    = (const float*)d_in[6];
  const float* Wc    = (const float*)d_in[7];
  const float* bc    = (const float*)d_in[8];
  const float* gamma = (const float*)d_in[9];
  const float* beta  = (const float*)d_in[10];
  float* out = (float*)d_out;

  char* ws = (char*)d_ws;
  size_t off = 0;
  auto alloc = [&](size_t bytes) {
    void* p = ws + off;
    off = (off + bytes + 255) & ~(size_t)255;
    return p;
  };
  unsigned short* hB   = (unsigned short*)alloc((size_t)NT * NH * 2);
  unsigned short* rhB  = (unsigned short*)alloc((size_t)NT * NH * 2);
  _Float16*       zH   = (_Float16*)alloc((size_t)NT * NH * 2);
  unsigned short* xT   = (unsigned short*)alloc((size_t)NS * NN * NB * ND * 2);
  unsigned short* Xa   = (unsigned short*)alloc((size_t)NS * NN * NB * ND * 2);
  unsigned short* Wt_zr = (unsigned short*)alloc((size_t)256 * 192 * 2);
  unsigned short* Wt_c  = (unsigned short*)alloc((size_t)128 * 192 * 2);
  float* dinv = (float*)alloc(NN * 4);
  float* dsq  = (float*)alloc(NN * 4);
  int* deg       = (int*)alloc(NN * 4);
  int* row_start = (int*)alloc((NN + 1) * 4);
  int* cursor    = (int*)alloc(NN * 4);
  int* csr_src   = (int*)alloc(NE * 4);
  int* perm      = (int*)alloc(NN * 4);

  const int* e_src = ei;
  const int* e_dst = ei + NE;

  hipMemsetAsync(hB, 0, (size_t)NT * NH * 2, stream);
  hipMemsetAsync(deg, 0, NN * 4, stream);
  hipMemsetAsync(cursor, 0, NN * 4, stream);
  hipMemsetAsync(d_out, 0, (size_t)NB * NH * 4, stream);

  k_count<<<NE / 256, 256, 0, stream>>>(e_dst, deg);
  k_scan<<<1, 256, 0, stream>>>(deg, row_start, dinv, dsq);
  k_scatter<<<NE / 256, 256, 0, stream>>>(e_src, e_dst, row_start, cursor, csr_src);
  k_perm<<<1, 256, 0, stream>>>(deg, perm);
  k_wcvt<<<256, 192, 0, stream>>>(Wz, Wr, Wc, Wt_zr, Wt_c);
  k_xT<<<16384, 256, 0, stream>>>(x, dinv, xT);
  k_aggX2<<<16384, 256, 0, stream>>>(xT, row_start, csr_src, dinv, Xa);

  for (int s = 0; s < NS; s++) {
    k_zrF<<<NN / 2, 256, 0, stream>>>(Xa, hB, Wt_zr, row_start, csr_src, dinv,
                                      perm, bz, br, zH, rhB, s);
    k_cF<<<NN / 2, 256, 0, stream>>>(Xa, rhB, zH, Wt_c, row_start, csr_src, dinv,
                                     dsq, perm, bc, gamma, beta, hB, s);
  }
  k_pool<<<128, 128, 0, stream>>>(hB, dsq, out);
}